// Round 1
// baseline (591.285 us; speedup 1.0000x reference)
//
#include <hip/hip_runtime.h>

typedef __bf16 bf16;
typedef __bf16 bf16x8 __attribute__((ext_vector_type(8)));
typedef __bf16 bf16x4 __attribute__((ext_vector_type(4)));
typedef float  f32x4  __attribute__((ext_vector_type(4)));

#define NB 4
#define NS 2048
#define ND 1024
#define NH 16
#define NDK 64
#define NFF 4096
#define NM (NB*NS)   // 8192 rows

__device__ __forceinline__ void load_lds16(const void* g, void* l) {
  __builtin_amdgcn_global_load_lds(
      (const __attribute__((address_space(1))) void*)g,
      (__attribute__((address_space(3))) void*)l, 16, 0, 0);
}

// ---------------------------------------------------------------- cvt src
__global__ __launch_bounds__(256)
void cvt_f32_bf16(const float* __restrict__ in, bf16* __restrict__ out, int n) {
  int i = (blockIdx.x * 256 + threadIdx.x) * 4;
  if (i < n) {
    float4 v = *(const float4*)&in[i];
    bf16x4 o;
    o[0] = (bf16)v.x; o[1] = (bf16)v.y; o[2] = (bf16)v.z; o[3] = (bf16)v.w;
    *(bf16x4*)&out[i] = o;
  }
}

// ------------------------------------------------- transpose fp32 -> bf16^T
// in[bz][R][C] fp32 -> out[bz][C][R] bf16
__global__ __launch_bounds__(256)
void transpose_cvt(const float* __restrict__ in, bf16* __restrict__ out,
                   int R, int C, size_t in_bs, size_t out_bs) {
  __shared__ float t[32][33];
  int bx = blockIdx.x, by = blockIdx.y, bz = blockIdx.z;
  const float* ip = in + (size_t)bz * in_bs + (size_t)(bx * 32) * C + by * 32;
  bf16* op = out + (size_t)bz * out_bs + (size_t)(by * 32) * R + bx * 32;
  int x = threadIdx.x & 31, y = threadIdx.x >> 5;  // y = 0..7
#pragma unroll
  for (int yy = 0; yy < 32; yy += 8)
    t[y + yy][x] = ip[(size_t)(y + yy) * C + x];
  __syncthreads();
#pragma unroll
  for (int yy = 0; yy < 32; yy += 8)
    op[(size_t)(y + yy) * R + x] = (bf16)t[x][y + yy];
}

// ------------------------------------------------- transpose V (bf16->bf16)
// v[bh][S][DK] -> vT[bh][DK][S]
__global__ __launch_bounds__(256)
void transpose_v(const bf16* __restrict__ v, bf16* __restrict__ vT) {
  __shared__ bf16 t[64][72];
  int st = blockIdx.x;   // S/64
  int bh = blockIdx.y;
  const bf16* ip = v + ((size_t)bh * NS + st * 64) * NDK;
  bf16* op = vT + (size_t)bh * NDK * NS + st * 64;
  int tid = threadIdx.x;
#pragma unroll
  for (int c = tid; c < 512; c += 256) {
    int r = c >> 3, q = c & 7;
    bf16x8 d = *(const bf16x8*)&ip[(size_t)r * NDK + q * 8];
#pragma unroll
    for (int j = 0; j < 8; j++) t[r][q * 8 + j] = d[j];
  }
  __syncthreads();
#pragma unroll
  for (int c = tid; c < 512; c += 256) {
    int dv = c >> 3, sq = c & 7;
    bf16x8 d;
#pragma unroll
    for (int j = 0; j < 8; j++) d[j] = t[sq * 8 + j][dv];
    *(bf16x8*)&op[(size_t)dv * NS + sq * 8] = d;
  }
}

// ---------------------------------------------------------------- GEMM
// C[M,N] = A[M,K] * Bt[N,K]^T (+bias, epilogue variants)
// EPI 0: QKV scatter (out bf16 q|k|v [B,H,S,DK], bias0/1/2 = bq/bk/bv)
// EPI 1: bf16 out, bias + relu
// EPI 2: f32 out, bias
template<int EPI>
__global__ __launch_bounds__(256)
void gemm_bt(const bf16* __restrict__ A, const bf16* __restrict__ Bt,
             const float* __restrict__ bias0, const float* __restrict__ bias1,
             const float* __restrict__ bias2, void* __restrict__ out0,
             int M, int N, int K) {
  __shared__ __align__(16) bf16 lA[128 * 32];
  __shared__ __align__(16) bf16 lB[128 * 32];
  const int tid = threadIdx.x;
  const int lane = tid & 63;
  const int w = tid >> 6;
  const int wr = w >> 1, wc = w & 1;
  const int blane = lane & 15, glane = lane >> 4;
  const int bm = blockIdx.x * 128;
  const int bn = blockIdx.y * 128;

  f32x4 acc[4][4] = {};
  const bf16* aBase = A + (size_t)bm * K;
  const bf16* bBase = Bt + (size_t)bn * K;
  const int c0 = tid, c1 = tid + 256;

  for (int kt = 0; kt < K; kt += 32) {
    const bf16* ag = aBase + kt;
    const bf16* bg = bBase + kt;
    load_lds16(ag + (size_t)(c0 >> 2) * K + (c0 & 3) * 8, &lA[c0 * 8]);
    load_lds16(ag + (size_t)(c1 >> 2) * K + (c1 & 3) * 8, &lA[c1 * 8]);
    load_lds16(bg + (size_t)(c0 >> 2) * K + (c0 & 3) * 8, &lB[c0 * 8]);
    load_lds16(bg + (size_t)(c1 >> 2) * K + (c1 & 3) * 8, &lB[c1 * 8]);
    __syncthreads();
    bf16x8 af[4], bfr[4];
#pragma unroll
    for (int m = 0; m < 4; m++) {
      int row = wr * 64 + m * 16 + blane;
      af[m] = *(const bf16x8*)&lA[row * 32 + glane * 8];
    }
#pragma unroll
    for (int n = 0; n < 4; n++) {
      int row = wc * 64 + n * 16 + blane;
      bfr[n] = *(const bf16x8*)&lB[row * 32 + glane * 8];
    }
#pragma unroll
    for (int m = 0; m < 4; m++)
#pragma unroll
      for (int n = 0; n < 4; n++)
        acc[m][n] = __builtin_amdgcn_mfma_f32_16x16x32_bf16(af[m], bfr[n], acc[m][n], 0, 0, 0);
    __syncthreads();
  }

#pragma unroll
  for (int m = 0; m < 4; m++) {
#pragma unroll
    for (int n = 0; n < 4; n++) {
      int col = bn + wc * 64 + n * 16 + blane;
      if (EPI == 0) {
        int sel = col >> 10;
        int hh = (col & 1023) >> 6;
        int dv = col & 63;
        const float* bp = (sel == 0) ? bias0 : (sel == 1) ? bias1 : bias2;
        float bias = bp[col & 1023];
        bf16* outb = (bf16*)out0 + (size_t)sel * NB * NH * NS * NDK;
#pragma unroll
        for (int i = 0; i < 4; i++) {
          int row = bm + wr * 64 + m * 16 + glane * 4 + i;
          int b_ = row >> 11, s_ = row & 2047;
          outb[(((size_t)(b_ * NH + hh) * NS + s_) * NDK) + dv] = (bf16)(acc[m][n][i] + bias);
        }
      } else if (EPI == 1) {
        float bias = bias0[col];
#pragma unroll
        for (int i = 0; i < 4; i++) {
          int row = bm + wr * 64 + m * 16 + glane * 4 + i;
          float v = acc[m][n][i] + bias;
          v = v > 0.f ? v : 0.f;
          ((bf16*)out0)[(size_t)row * N + col] = (bf16)v;
        }
      } else {
        float bias = bias0[col];
#pragma unroll
        for (int i = 0; i < 4; i++) {
          int row = bm + wr * 64 + m * 16 + glane * 4 + i;
          ((float*)out0)[(size_t)row * N + col] = acc[m][n][i] + bias;
        }
      }
    }
  }
}

// ---------------------------------------------------------------- flash attn
// q,k: [B*H][S][DK] bf16 ; vT: [B*H][DK][S] bf16 ; o: [B][S][H*DK] bf16
__global__ __launch_bounds__(256)
void flash_attn(const bf16* __restrict__ q, const bf16* __restrict__ k,
                const bf16* __restrict__ vT, bf16* __restrict__ o) {
  __shared__ __align__(16) bf16 lK[64 * 64];      // [t][dk], 16B chunks swizzled
  __shared__ __align__(16) bf16 lV[64 * 64];      // [dv][t], 16B chunks swizzled
  __shared__ __align__(16) bf16 lP[4][16 * 64];   // per-wave P, swizzled
  const int tid = threadIdx.x, lane = tid & 63, w = tid >> 6;
  const int blane = lane & 15, glane = lane >> 4;
  const int bh = blockIdx.y;
  const int qt = blockIdx.x;
  const size_t hb = (size_t)bh * NS * NDK;

  const int qrow = qt * 64 + w * 16 + blane;
  bf16x8 qf[2];
  qf[0] = *(const bf16x8*)&q[hb + (size_t)qrow * NDK + glane * 8];
  qf[1] = *(const bf16x8*)&q[hb + (size_t)qrow * NDK + 32 + glane * 8];

  f32x4 of[4] = {};
  float mrun[4], lrun[4];
#pragma unroll
  for (int i = 0; i < 4; i++) { mrun[i] = -1e30f; lrun[i] = 0.f; }
  const float scale = 0.125f;
  const int c0 = tid, c1 = tid + 256;

  for (int kv = 0; kv < NS; kv += 64) {
    __syncthreads();
    {
      const bf16* kg = k + hb + (size_t)kv * NDK;
      const bf16* vg = vT + hb + kv;
      int r = c0 >> 3, qg = (c0 & 7) ^ (r & 7);
      load_lds16(kg + (size_t)r * NDK + qg * 8, &lK[c0 * 8]);
      load_lds16(vg + (size_t)r * NS + qg * 8, &lV[c0 * 8]);
      r = c1 >> 3; qg = (c1 & 7) ^ (r & 7);
      load_lds16(kg + (size_t)r * NDK + qg * 8, &lK[c1 * 8]);
      load_lds16(vg + (size_t)r * NS + qg * 8, &lV[c1 * 8]);
    }
    __syncthreads();

    // QK^T: scores 16 x 64 per wave
    f32x4 sf[4];
#pragma unroll
    for (int c = 0; c < 4; c++) {
      int t = c * 16 + blane;
      bf16x8 kf0 = *(const bf16x8*)&lK[t * 64 + ((glane ^ (t & 7)) * 8)];
      bf16x8 kf1 = *(const bf16x8*)&lK[t * 64 + (((4 + glane) ^ (t & 7)) * 8)];
      f32x4 z = {};
      z = __builtin_amdgcn_mfma_f32_16x16x32_bf16(qf[0], kf0, z, 0, 0, 0);
      sf[c] = __builtin_amdgcn_mfma_f32_16x16x32_bf16(qf[1], kf1, z, 0, 0, 0);
    }
#pragma unroll
    for (int c = 0; c < 4; c++)
#pragma unroll
      for (int i = 0; i < 4; i++) sf[c][i] *= scale;

    // online softmax (rows: glane*4+i, cols across blane & c)
#pragma unroll
    for (int i = 0; i < 4; i++) {
      float mloc = fmaxf(fmaxf(sf[0][i], sf[1][i]), fmaxf(sf[2][i], sf[3][i]));
#pragma unroll
      for (int d = 1; d < 16; d <<= 1) mloc = fmaxf(mloc, __shfl_xor(mloc, d));
      float mn = fmaxf(mrun[i], mloc);
      float al = __expf(mrun[i] - mn);
      mrun[i] = mn;
      float rs = 0.f;
#pragma unroll
      for (int c = 0; c < 4; c++) {
        float p = __expf(sf[c][i] - mn);
        sf[c][i] = p;
        rs += p;
      }
#pragma unroll
      for (int d = 1; d < 16; d <<= 1) rs += __shfl_xor(rs, d);
      lrun[i] = lrun[i] * al + rs;
#pragma unroll
      for (int c = 0; c < 4; c++) of[c][i] *= al;
    }

    // P (C-layout) -> LDS (swizzled) -> A-layout frags
#pragma unroll
    for (int c = 0; c < 4; c++) {
      int t = c * 16 + blane;
#pragma unroll
      for (int i = 0; i < 4; i++) {
        int r = glane * 4 + i;
        lP[w][r * 64 + (((t >> 3) ^ (r & 7)) * 8) + (t & 7)] = (bf16)sf[c][i];
      }
    }
#pragma unroll
    for (int ts = 0; ts < 2; ts++) {
      int pr = blane;
      bf16x8 pf = *(const bf16x8*)&lP[w][pr * 64 + (((ts * 4 + glane) ^ (pr & 7)) * 8)];
#pragma unroll
      for (int c = 0; c < 4; c++) {
        int dv = c * 16 + blane;
        bf16x8 vf = *(const bf16x8*)&lV[dv * 64 + (((ts * 4 + glane) ^ (dv & 7)) * 8)];
        of[c] = __builtin_amdgcn_mfma_f32_16x16x32_bf16(pf, vf, of[c], 0, 0, 0);
      }
    }
  }

  float inv[4];
#pragma unroll
  for (int i = 0; i < 4; i++) inv[i] = 1.0f / lrun[i];
  int b_ = bh >> 4, h_ = bh & 15;
#pragma unroll
  for (int c = 0; c < 4; c++) {
    int dv = c * 16 + blane;
#pragma unroll
    for (int i = 0; i < 4; i++) {
      int s_ = qt * 64 + w * 16 + glane * 4 + i;
      o[((size_t)(b_ * NS + s_) * (NH * NDK)) + h_ * NDK + dv] = (bf16)(of[c][i] * inv[i]);
    }
  }
}

// ---------------------------------------------------------------- LN(residual)
template<int WB>
__global__ __launch_bounds__(256)
void ln_res(const float* __restrict__ a, const float* __restrict__ b,
            const float* __restrict__ g, const float* __restrict__ be,
            float* __restrict__ y, bf16* __restrict__ yb) {
  int row = blockIdx.x;
  int tid = threadIdx.x;
  const float4* a4 = (const float4*)(a + (size_t)row * ND);
  const float4* b4 = (const float4*)(b + (size_t)row * ND);
  float4 av = a4[tid], bv = b4[tid];
  float x0 = av.x + bv.x, x1 = av.y + bv.y, x2 = av.z + bv.z, x3 = av.w + bv.w;
  float s = x0 + x1 + x2 + x3;
  float qq_ = x0 * x0 + x1 * x1 + x2 * x2 + x3 * x3;
#pragma unroll
  for (int d = 1; d < 64; d <<= 1) { s += __shfl_xor(s, d); qq_ += __shfl_xor(qq_, d); }
  __shared__ float ss[4], sq[4];
  int w = tid >> 6, lane = tid & 63;
  if (lane == 0) { ss[w] = s; sq[w] = qq_; }
  __syncthreads();
  s = ss[0] + ss[1] + ss[2] + ss[3];
  qq_ = sq[0] + sq[1] + sq[2] + sq[3];
  float mu = s * (1.0f / ND);
  float var = qq_ * (1.0f / ND) - mu * mu;
  float rs = 1.0f / sqrtf(var + 1e-5f);
  const float4* g4 = (const float4*)g;
  const float4* e4 = (const float4*)be;
  float4 gv = g4[tid], ev = e4[tid];
  float o0 = (x0 - mu) * rs * gv.x + ev.x;
  float o1 = (x1 - mu) * rs * gv.y + ev.y;
  float o2 = (x2 - mu) * rs * gv.z + ev.z;
  float o3 = (x3 - mu) * rs * gv.w + ev.w;
  float4 ov = {o0, o1, o2, o3};
  *(float4*)(y + (size_t)row * ND + tid * 4) = ov;
  if (WB) {
    bf16x4 wv;
    wv[0] = (bf16)o0; wv[1] = (bf16)o1; wv[2] = (bf16)o2; wv[3] = (bf16)o3;
    *(bf16x4*)&yb[(size_t)row * ND + tid * 4] = wv;
  }
}

// ---------------------------------------------------------------- launch
extern "C" void kernel_launch(void* const* d_in, const int* in_sizes, int n_in,
                              void* d_out, int out_size, void* d_ws, size_t ws_size,
                              hipStream_t stream) {
  const float* src = (const float*)d_in[0];
  const float* wq  = (const float*)d_in[1];
  const float* bq  = (const float*)d_in[2];
  const float* wk  = (const float*)d_in[3];
  const float* bk  = (const float*)d_in[4];
  const float* wv  = (const float*)d_in[5];
  const float* bv  = (const float*)d_in[6];
  const float* wo  = (const float*)d_in[7];
  const float* bo  = (const float*)d_in[8];
  const float* g1  = (const float*)d_in[9];
  const float* be1 = (const float*)d_in[10];
  const float* w1  = (const float*)d_in[11];
  const float* b1  = (const float*)d_in[12];
  const float* w2  = (const float*)d_in[13];
  const float* b2  = (const float*)d_in[14];
  const float* g2  = (const float*)d_in[15];
  const float* be2 = (const float*)d_in[16];

  char* ws = (char*)d_ws;
  bf16*  srcb  = (bf16*)(ws + 0);            // 16 MiB
  bf16*  wqkvT = (bf16*)(ws + 16777216);     // 6 MiB  [3072][1024]
  bf16*  woT   = (bf16*)(ws + 23068672);     // 2 MiB  [1024][1024]
  bf16*  w1T   = (bf16*)(ws + 25165824);     // 8 MiB  [4096][1024]
  bf16*  w2T   = (bf16*)(ws + 33554432);     // 8 MiB  [1024][4096]
  bf16*  qkv   = (bf16*)(ws + 41943040);     // 48 MiB q|k|v [BH][S][DK]
  bf16*  vT    = (bf16*)(ws + 92274688);     // 16 MiB [BH][DK][S]
  bf16*  attno = (bf16*)(ws + 109051904);    // 16 MiB [B][S][H*DK]
  float* tmpf  = (float*)(ws + 125829120);   // 32 MiB attn_out / ff
  float* x     = (float*)(ws + 159383552);   // 32 MiB
  bf16*  xb    = (bf16*)(ws + 192937984);    // 16 MiB  (total 200 MiB)
  bf16*  hbuf  = qkv;                         // 64 MiB alias (qkv+vT dead after attn)

  const size_t QKVSZ = (size_t)NB * NH * NS * NDK;  // 8388608

  cvt_f32_bf16<<<8192, 256, 0, stream>>>(src, srcb, NM * ND);
  transpose_cvt<<<dim3(32, 2, 16), 256, 0, stream>>>(wq, wqkvT,               1024, 64, 65536, 65536);
  transpose_cvt<<<dim3(32, 2, 16), 256, 0, stream>>>(wk, wqkvT + 1024 * 1024, 1024, 64, 65536, 65536);
  transpose_cvt<<<dim3(32, 2, 16), 256, 0, stream>>>(wv, wqkvT + 2048 * 1024, 1024, 64, 65536, 65536);
  transpose_cvt<<<dim3(32, 32, 1), 256, 0, stream>>>(wo, woT, 1024, 1024, 0, 0);
  transpose_cvt<<<dim3(32, 128, 1), 256, 0, stream>>>(w1, w1T, 1024, 4096, 0, 0);
  transpose_cvt<<<dim3(128, 32, 1), 256, 0, stream>>>(w2, w2T, 4096, 1024, 0, 0);

  gemm_bt<0><<<dim3(64, 24), 256, 0, stream>>>(srcb, wqkvT, bq, bk, bv, qkv, NM, 3072, 1024);
  transpose_v<<<dim3(32, 64), 256, 0, stream>>>(qkv + 2 * QKVSZ, vT);
  flash_attn<<<dim3(32, 64), 256, 0, stream>>>(qkv, qkv + QKVSZ, vT, attno);
  gemm_bt<2><<<dim3(64, 8), 256, 0, stream>>>(attno, woT, bo, nullptr, nullptr, tmpf, NM, 1024, 1024);
  ln_res<1><<<8192, 256, 0, stream>>>(src, tmpf, g1, be1, x, xb);
  gemm_bt<1><<<dim3(64, 32), 256, 0, stream>>>(xb, w1T, b1, nullptr, nullptr, hbuf, NM, 4096, 1024);
  gemm_bt<2><<<dim3(64, 8), 256, 0, stream>>>(hbuf, w2T, b2, nullptr, nullptr, tmpf, NM, 1024, 4096);
  ln_res<0><<<8192, 256, 0, stream>>>(x, tmpf, g2, be2, (float*)d_out, nullptr);
}

// Round 2
// 545.094 us; speedup vs baseline: 1.0847x; 1.0847x over previous
//
#include <hip/hip_runtime.h>

typedef __bf16 bf16;
typedef __bf16 bf16x8 __attribute__((ext_vector_type(8)));
typedef __bf16 bf16x4 __attribute__((ext_vector_type(4)));
typedef float  f32x4  __attribute__((ext_vector_type(4)));
typedef float  f32x16 __attribute__((ext_vector_type(16)));
typedef unsigned int u32;

#define NB 4
#define NS 2048
#define ND 1024
#define NH 16
#define NDK 64
#define NFF 4096
#define NM (NB*NS)   // 8192 rows

__device__ __forceinline__ void load_lds16(const void* g, void* l) {
  __builtin_amdgcn_global_load_lds(
      (const __attribute__((address_space(1))) void*)g,
      (__attribute__((address_space(3))) void*)l, 16, 0, 0);
}

__device__ __forceinline__ u32 pack2(float a, float b) {
  union { bf16 h[2]; u32 u; } z;
  z.h[0] = (bf16)a; z.h[1] = (bf16)b;
  return z.u;
}

// ---------------------------------------------------------------- cvt src
__global__ __launch_bounds__(256)
void cvt_f32_bf16(const float* __restrict__ in, bf16* __restrict__ out, int n) {
  int i = (blockIdx.x * 256 + threadIdx.x) * 4;
  if (i < n) {
    float4 v = *(const float4*)&in[i];
    bf16x4 o;
    o[0] = (bf16)v.x; o[1] = (bf16)v.y; o[2] = (bf16)v.z; o[3] = (bf16)v.w;
    *(bf16x4*)&out[i] = o;
  }
}

// ------------------------------------------------- transpose fp32 -> bf16^T
__global__ __launch_bounds__(256)
void transpose_cvt(const float* __restrict__ in, bf16* __restrict__ out,
                   int R, int C, size_t in_bs, size_t out_bs) {
  __shared__ float t[32][33];
  int bx = blockIdx.x, by = blockIdx.y, bz = blockIdx.z;
  const float* ip = in + (size_t)bz * in_bs + (size_t)(bx * 32) * C + by * 32;
  bf16* op = out + (size_t)bz * out_bs + (size_t)(by * 32) * R + bx * 32;
  int x = threadIdx.x & 31, y = threadIdx.x >> 5;
#pragma unroll
  for (int yy = 0; yy < 32; yy += 8)
    t[y + yy][x] = ip[(size_t)(y + yy) * C + x];
  __syncthreads();
#pragma unroll
  for (int yy = 0; yy < 32; yy += 8)
    op[(size_t)(y + yy) * R + x] = (bf16)t[x][y + yy];
}

// ------------------------------------------------- transpose V (bf16->bf16)
__global__ __launch_bounds__(256)
void transpose_v(const bf16* __restrict__ v, bf16* __restrict__ vT) {
  __shared__ bf16 t[64][72];
  int st = blockIdx.x;
  int bh = blockIdx.y;
  const bf16* ip = v + ((size_t)bh * NS + st * 64) * NDK;
  bf16* op = vT + (size_t)bh * NDK * NS + st * 64;
  int tid = threadIdx.x;
#pragma unroll
  for (int c = tid; c < 512; c += 256) {
    int r = c >> 3, q = c & 7;
    bf16x8 d = *(const bf16x8*)&ip[(size_t)r * NDK + q * 8];
#pragma unroll
    for (int j = 0; j < 8; j++) t[r][q * 8 + j] = d[j];
  }
  __syncthreads();
#pragma unroll
  for (int c = tid; c < 512; c += 256) {
    int dv = c >> 3, sq = c & 7;
    bf16x8 d;
#pragma unroll
    for (int j = 0; j < 8; j++) d[j] = t[sq * 8 + j][dv];
    *(bf16x8*)&op[(size_t)dv * NS + sq * 8] = d;
  }
}

// ---------------------------------------------------------------- GEMM
template<int EPI>
__global__ __launch_bounds__(256)
void gemm_bt(const bf16* __restrict__ A, const bf16* __restrict__ Bt,
             const float* __restrict__ bias0, const float* __restrict__ bias1,
             const float* __restrict__ bias2, void* __restrict__ out0,
             int M, int N, int K) {
  __shared__ __align__(16) bf16 lA[128 * 32];
  __shared__ __align__(16) bf16 lB[128 * 32];
  const int tid = threadIdx.x;
  const int lane = tid & 63;
  const int w = tid >> 6;
  const int wr = w >> 1, wc = w & 1;
  const int blane = lane & 15, glane = lane >> 4;
  const int bm = blockIdx.x * 128;
  const int bn = blockIdx.y * 128;

  f32x4 acc[4][4] = {};
  const bf16* aBase = A + (size_t)bm * K;
  const bf16* bBase = Bt + (size_t)bn * K;
  const int c0 = tid, c1 = tid + 256;

  for (int kt = 0; kt < K; kt += 32) {
    const bf16* ag = aBase + kt;
    const bf16* bg = bBase + kt;
    load_lds16(ag + (size_t)(c0 >> 2) * K + (c0 & 3) * 8, &lA[c0 * 8]);
    load_lds16(ag + (size_t)(c1 >> 2) * K + (c1 & 3) * 8, &lA[c1 * 8]);
    load_lds16(bg + (size_t)(c0 >> 2) * K + (c0 & 3) * 8, &lB[c0 * 8]);
    load_lds16(bg + (size_t)(c1 >> 2) * K + (c1 & 3) * 8, &lB[c1 * 8]);
    __syncthreads();
    bf16x8 af[4], bfr[4];
#pragma unroll
    for (int m = 0; m < 4; m++) {
      int row = wr * 64 + m * 16 + blane;
      af[m] = *(const bf16x8*)&lA[row * 32 + glane * 8];
    }
#pragma unroll
    for (int n = 0; n < 4; n++) {
      int row = wc * 64 + n * 16 + blane;
      bfr[n] = *(const bf16x8*)&lB[row * 32 + glane * 8];
    }
#pragma unroll
    for (int m = 0; m < 4; m++)
#pragma unroll
      for (int n = 0; n < 4; n++)
        acc[m][n] = __builtin_amdgcn_mfma_f32_16x16x32_bf16(af[m], bfr[n], acc[m][n], 0, 0, 0);
    __syncthreads();
  }

#pragma unroll
  for (int m = 0; m < 4; m++) {
#pragma unroll
    for (int n = 0; n < 4; n++) {
      int col = bn + wc * 64 + n * 16 + blane;
      if (EPI == 0) {
        int sel = col >> 10;
        int hh = (col & 1023) >> 6;
        int dv = col & 63;
        const float* bp = (sel == 0) ? bias0 : (sel == 1) ? bias1 : bias2;
        float bias = bp[col & 1023];
        bf16* outb = (bf16*)out0 + (size_t)sel * NB * NH * NS * NDK;
#pragma unroll
        for (int i = 0; i < 4; i++) {
          int row = bm + wr * 64 + m * 16 + glane * 4 + i;
          int b_ = row >> 11, s_ = row & 2047;
          outb[(((size_t)(b_ * NH + hh) * NS + s_) * NDK) + dv] = (bf16)(acc[m][n][i] + bias);
        }
      } else if (EPI == 1) {
        float bias = bias0[col];
#pragma unroll
        for (int i = 0; i < 4; i++) {
          int row = bm + wr * 64 + m * 16 + glane * 4 + i;
          float v = acc[m][n][i] + bias;
          v = v > 0.f ? v : 0.f;
          ((bf16*)out0)[(size_t)row * N + col] = (bf16)v;
        }
      } else {
        float bias = bias0[col];
#pragma unroll
        for (int i = 0; i < 4; i++) {
          int row = bm + wr * 64 + m * 16 + glane * 4 + i;
          ((float*)out0)[(size_t)row * N + col] = acc[m][n][i] + bias;
        }
      }
    }
  }
}

// ---------------------------------------------------------------- flash attn v2
// 8 waves x 32 q-rows, KVBLK=64, swapped-operand 32x32x16 MFMA, in-register softmax.
// q,k: [B*H][S][DK] bf16 ; vT: [B*H][DK][S] bf16 ; o: [B][S][H*DK] bf16
__global__ __launch_bounds__(512, 1)
void flash_attn2(const bf16* __restrict__ q, const bf16* __restrict__ k,
                 const bf16* __restrict__ vT, bf16* __restrict__ o) {
  __shared__ __align__(16) bf16 lK[2][64 * 64];
  __shared__ __align__(16) bf16 lV[2][64 * 64];
  const int tid = threadIdx.x, lane = tid & 63, w = tid >> 6;
  const int ql = lane & 31, hi = lane >> 5;
  const int bh = blockIdx.y, qt = blockIdx.x;
  const size_t hb = (size_t)bh * NS * NDK;
  const int qrow = qt * 256 + w * 32 + ql;

  // Q fragments: B-operand, col=q (lane-local), k = d = 16*ks + 8*hi + j
  bf16x8 qf[4];
#pragma unroll
  for (int ks = 0; ks < 4; ks++)
    qf[ks] = *(const bf16x8*)&q[hb + (size_t)qrow * NDK + ks * 16 + hi * 8];

  // staging source (pre-swizzled chunk so linear LDS dest + swizzled read works)
  const int srow = tid >> 3, sch = tid & 7;
  const bf16* ksrc = k  + hb + (size_t)srow * NDK + ((sch ^ (srow & 7)) * 8);
  const bf16* vsrc = vT + hb + (size_t)srow * NS  + ((sch ^ (srow & 7)) * 8);

  f32x16 o0 = {}, o1 = {};
  float mR = -3e38f, lR = 0.f;
  const float cl2 = 0.18033688f;  // (1/sqrt(64)) * log2(e)

  load_lds16(ksrc, &lK[0][tid * 8]);
  load_lds16(vsrc, &lV[0][tid * 8]);
  __syncthreads();

  const char* lKc = (const char*)&lK[0][0];
  const char* lVc = (const char*)&lV[0][0];
  const int swz = (ql & 7) << 4;

  for (int t = 0; t < NS / 64; t++) {
    const int cur = t & 1;
    if (t < NS / 64 - 1) {
      load_lds16(ksrc + (size_t)(t + 1) * 64 * NDK, &lK[cur ^ 1][tid * 8]);
      load_lds16(vsrc + (t + 1) * 64,               &lV[cur ^ 1][tid * 8]);
    }
    const char* Kb = lKc + cur * 8192;
    const char* Vb = lVc + cur * 8192;

    // ---- S^T = K * Q^T : C col = q (lane-local), row = t_local
    f32x16 st0 = {}, st1 = {};
#pragma unroll
    for (int ks = 0; ks < 4; ks++) {
      int byt = (32 * ks + 16 * hi) ^ swz;
      bf16x8 kf0 = *(const bf16x8*)(Kb + ql * 128 + byt);
      bf16x8 kf1 = *(const bf16x8*)(Kb + (32 + ql) * 128 + byt);
      st0 = __builtin_amdgcn_mfma_f32_32x32x16_bf16(kf0, qf[ks], st0, 0, 0, 0);
      st1 = __builtin_amdgcn_mfma_f32_32x32x16_bf16(kf1, qf[ks], st1, 0, 0, 0);
    }

    // ---- online softmax, all in-register (row = own q; halves join via one shfl)
    float mx = st0[0];
#pragma unroll
    for (int r = 1; r < 16; r++) mx = fmaxf(mx, st0[r]);
#pragma unroll
    for (int r = 0; r < 16; r++) mx = fmaxf(mx, st1[r]);
    mx = fmaxf(mx, __shfl_xor(mx, 32));
    float mn = fmaxf(mR, mx);
    float al = exp2f((mR - mn) * cl2);
    float cmn = mn * cl2;
    float ls = 0.f;
#pragma unroll
    for (int r = 0; r < 16; r++) { float p = exp2f(fmaf(st0[r], cl2, -cmn)); st0[r] = p; ls += p; }
#pragma unroll
    for (int r = 0; r < 16; r++) { float p = exp2f(fmaf(st1[r], cl2, -cmn)); st1[r] = p; ls += p; }
    ls += __shfl_xor(ls, 32);
    lR = lR * al + ls;
    mR = mn;
#pragma unroll
    for (int r = 0; r < 16; r++) { o0[r] *= al; o1[r] *= al; }

    // ---- P -> bf16 B-fragments (cross-half exchange) + PV (swapped: O^T)
#pragma unroll
    for (int tt = 0; tt < 2; tt++) {
      f32x16 stv = (tt == 0) ? st0 : st1;
      u32 wv[8];
#pragma unroll
      for (int i = 0; i < 8; i++) wv[i] = pack2(stv[2 * i], stv[2 * i + 1]);
#pragma unroll
      for (int kk = 0; kk < 2; kk++) {
        const int base = 4 * kk;
        u32 x0 = hi ? wv[base + 0] : wv[base + 2];
        u32 x1 = hi ? wv[base + 1] : wv[base + 3];
        u32 y0 = (u32)__shfl_xor((int)x0, 32);
        u32 y1 = (u32)__shfl_xor((int)x1, 32);
        union { u32 u[4]; bf16x8 v; } pf;
        pf.u[0] = hi ? y0 : wv[base + 0];
        pf.u[1] = hi ? y1 : wv[base + 1];
        pf.u[2] = hi ? wv[base + 2] : y0;
        pf.u[3] = hi ? wv[base + 3] : y1;
        const int ks = 2 * tt + kk;
        int vbyt = (32 * ks + 16 * hi) ^ swz;
        bf16x8 vf0 = *(const bf16x8*)(Vb + ql * 128 + vbyt);
        bf16x8 vf1 = *(const bf16x8*)(Vb + (32 + ql) * 128 + vbyt);
        o0 = __builtin_amdgcn_mfma_f32_32x32x16_bf16(vf0, pf.v, o0, 0, 0, 0);
        o1 = __builtin_amdgcn_mfma_f32_32x32x16_bf16(vf1, pf.v, o1, 0, 0, 0);
      }
    }
    __syncthreads();
  }

  // ---- epilogue: O^T regs -> out. lane holds col q (own), rows dv.
  float invl = 1.0f / lR;
  int b_ = bh >> 4, h_ = bh & 15;
  bf16* ob = o + ((size_t)(b_ * NS + qrow) * (NH * NDK)) + h_ * NDK;
#pragma unroll
  for (int rp = 0; rp < 8; rp++) {
    int dv = 8 * (rp >> 1) + 2 * (rp & 1) + 4 * hi;
    *(u32*)&ob[dv]      = pack2(o0[2 * rp] * invl, o0[2 * rp + 1] * invl);
    *(u32*)&ob[dv + 32] = pack2(o1[2 * rp] * invl, o1[2 * rp + 1] * invl);
  }
}

// ---------------------------------------------------------------- LN(residual)
template<int WB>
__global__ __launch_bounds__(256)
void ln_res(const float* __restrict__ a, const float* __restrict__ b,
            const float* __restrict__ g, const float* __restrict__ be,
            float* __restrict__ y, bf16* __restrict__ yb) {
  int row = blockIdx.x;
  int tid = threadIdx.x;
  const float4* a4 = (const float4*)(a + (size_t)row * ND);
  const float4* b4 = (const float4*)(b + (size_t)row * ND);
  float4 av = a4[tid], bv = b4[tid];
  float x0 = av.x + bv.x, x1 = av.y + bv.y, x2 = av.z + bv.z, x3 = av.w + bv.w;
  float s = x0 + x1 + x2 + x3;
  float qq_ = x0 * x0 + x1 * x1 + x2 * x2 + x3 * x3;
#pragma unroll
  for (int d = 1; d < 64; d <<= 1) { s += __shfl_xor(s, d); qq_ += __shfl_xor(qq_, d); }
  __shared__ float ss[4], sq[4];
  int w = tid >> 6, lane = tid & 63;
  if (lane == 0) { ss[w] = s; sq[w] = qq_; }
  __syncthreads();
  s = ss[0] + ss[1] + ss[2] + ss[3];
  qq_ = sq[0] + sq[1] + sq[2] + sq[3];
  float mu = s * (1.0f / ND);
  float var = qq_ * (1.0f / ND) - mu * mu;
  float rs = 1.0f / sqrtf(var + 1e-5f);
  const float4* g4 = (const float4*)g;
  const float4* e4 = (const float4*)be;
  float4 gv = g4[tid], ev = e4[tid];
  float o0 = (x0 - mu) * rs * gv.x + ev.x;
  float o1 = (x1 - mu) * rs * gv.y + ev.y;
  float o2 = (x2 - mu) * rs * gv.z + ev.z;
  float o3 = (x3 - mu) * rs * gv.w + ev.w;
  float4 ov = {o0, o1, o2, o3};
  *(float4*)(y + (size_t)row * ND + tid * 4) = ov;
  if (WB) {
    bf16x4 wv;
    wv[0] = (bf16)o0; wv[1] = (bf16)o1; wv[2] = (bf16)o2; wv[3] = (bf16)o3;
    *(bf16x4*)&yb[(size_t)row * ND + tid * 4] = wv;
  }
}

// ---------------------------------------------------------------- launch
extern "C" void kernel_launch(void* const* d_in, const int* in_sizes, int n_in,
                              void* d_out, int out_size, void* d_ws, size_t ws_size,
                              hipStream_t stream) {
  const float* src = (const float*)d_in[0];
  const float* wq  = (const float*)d_in[1];
  const float* bq  = (const float*)d_in[2];
  const float* wk  = (const float*)d_in[3];
  const float* bk  = (const float*)d_in[4];
  const float* wv  = (const float*)d_in[5];
  const float* bv  = (const float*)d_in[6];
  const float* wo  = (const float*)d_in[7];
  const float* bo  = (const float*)d_in[8];
  const float* g1  = (const float*)d_in[9];
  const float* be1 = (const float*)d_in[10];
  const float* w1  = (const float*)d_in[11];
  const float* b1  = (const float*)d_in[12];
  const float* w2  = (const float*)d_in[13];
  const float* b2  = (const float*)d_in[14];
  const float* g2  = (const float*)d_in[15];
  const float* be2 = (const float*)d_in[16];

  char* ws = (char*)d_ws;
  bf16*  srcb  = (bf16*)(ws + 0);            // 16 MiB
  bf16*  wqkvT = (bf16*)(ws + 16777216);     // 6 MiB  [3072][1024]
  bf16*  woT   = (bf16*)(ws + 23068672);     // 2 MiB  [1024][1024]
  bf16*  w1T   = (bf16*)(ws + 25165824);     // 8 MiB  [4096][1024]
  bf16*  w2T   = (bf16*)(ws + 33554432);     // 8 MiB  [1024][4096]
  bf16*  qkv   = (bf16*)(ws + 41943040);     // 48 MiB q|k|v [BH][S][DK]
  bf16*  vT    = (bf16*)(ws + 92274688);     // 16 MiB [BH][DK][S]
  bf16*  attno = (bf16*)(ws + 109051904);    // 16 MiB [B][S][H*DK]
  float* tmpf  = (float*)(ws + 125829120);   // 32 MiB attn_out / ff
  float* x     = (float*)(ws + 159383552);   // 32 MiB
  bf16*  xb    = (bf16*)(ws + 192937984);    // 16 MiB
  bf16*  hbuf  = qkv;                         // 64 MiB alias (qkv+vT dead after attn)

  const size_t QKVSZ = (size_t)NB * NH * NS * NDK;

  cvt_f32_bf16<<<8192, 256, 0, stream>>>(src, srcb, NM * ND);
  transpose_cvt<<<dim3(32, 2, 16), 256, 0, stream>>>(wq, wqkvT,               1024, 64, 65536, 65536);
  transpose_cvt<<<dim3(32, 2, 16), 256, 0, stream>>>(wk, wqkvT + 1024 * 1024, 1024, 64, 65536, 65536);
  transpose_cvt<<<dim3(32, 2, 16), 256, 0, stream>>>(wv, wqkvT + 2048 * 1024, 1024, 64, 65536, 65536);
  transpose_cvt<<<dim3(32, 32, 1), 256, 0, stream>>>(wo, woT, 1024, 1024, 0, 0);
  transpose_cvt<<<dim3(32, 128, 1), 256, 0, stream>>>(w1, w1T, 1024, 4096, 0, 0);
  transpose_cvt<<<dim3(128, 32, 1), 256, 0, stream>>>(w2, w2T, 4096, 1024, 0, 0);

  gemm_bt<0><<<dim3(64, 24), 256, 0, stream>>>(srcb, wqkvT, bq, bk, bv, qkv, NM, 3072, 1024);
  transpose_v<<<dim3(32, 64), 256, 0, stream>>>(qkv + 2 * QKVSZ, vT);
  flash_attn2<<<dim3(8, 64), 512, 0, stream>>>(qkv, qkv + QKVSZ, vT, attno);
  gemm_bt<2><<<dim3(64, 8), 256, 0, stream>>>(attno, woT, bo, nullptr, nullptr, tmpf, NM, 1024, 1024);
  ln_res<1><<<8192, 256, 0, stream>>>(src, tmpf, g1, be1, x, xb);
  gemm_bt<1><<<dim3(64, 32), 256, 0, stream>>>(xb, w1T, b1, nullptr, nullptr, hbuf, NM, 4096, 1024);
  gemm_bt<2><<<dim3(64, 8), 256, 0, stream>>>(hbuf, w2T, b2, nullptr, nullptr, tmpf, NM, 1024, 4096);
  ln_res<0><<<8192, 256, 0, stream>>>(x, tmpf, g2, be2, (float*)d_out, nullptr);
}

// Round 3
// 523.473 us; speedup vs baseline: 1.1295x; 1.0413x over previous
//
#include <hip/hip_runtime.h>

typedef __bf16 bf16;
typedef __bf16 bf16x8 __attribute__((ext_vector_type(8)));
typedef __bf16 bf16x4 __attribute__((ext_vector_type(4)));
typedef float  f32x4  __attribute__((ext_vector_type(4)));
typedef float  f32x16 __attribute__((ext_vector_type(16)));
typedef unsigned int u32;
typedef int i32x2 __attribute__((ext_vector_type(2)));

#define NB 4
#define NS 2048
#define ND 1024
#define NH 16
#define NDK 64
#define NFF 4096
#define NM (NB*NS)   // 8192 rows

__device__ __forceinline__ void load_lds16(const void* g, void* l) {
  __builtin_amdgcn_global_load_lds(
      (const __attribute__((address_space(1))) void*)g,
      (__attribute__((address_space(3))) void*)l, 16, 0, 0);
}

__device__ __forceinline__ u32 pack2(float a, float b) {
  union { bf16 h[2]; u32 u; } z;
  z.h[0] = (bf16)a; z.h[1] = (bf16)b;
  return z.u;
}

// v_permlane32_swap: res[0][l] = l<32 ? A[l] : B[l-32] ; res[1][l] = l<32 ? A[l+32] : B[l]
__device__ __forceinline__ i32x2 pswap(u32 a, u32 b) {
#if __has_builtin(__builtin_amdgcn_permlane32_swap)
  return __builtin_amdgcn_permlane32_swap((int)a, (int)b, false, false);
#else
  u32 x = a, y = b;
  asm volatile("v_permlane32_swap_b32 %0, %1" : "+v"(x), "+v"(y));
  i32x2 r; r[0] = (int)x; r[1] = (int)y; return r;
#endif
}

// ---------------------------------------------------------------- cvt src
__global__ __launch_bounds__(256)
void cvt_f32_bf16(const float* __restrict__ in, bf16* __restrict__ out, int n) {
  int i = (blockIdx.x * 256 + threadIdx.x) * 4;
  if (i < n) {
    float4 v = *(const float4*)&in[i];
    bf16x4 o;
    o[0] = (bf16)v.x; o[1] = (bf16)v.y; o[2] = (bf16)v.z; o[3] = (bf16)v.w;
    *(bf16x4*)&out[i] = o;
  }
}

// ------------------------------------------------- transpose fp32 -> bf16^T
__global__ __launch_bounds__(256)
void transpose_cvt(const float* __restrict__ in, bf16* __restrict__ out,
                   int R, int C, size_t in_bs, size_t out_bs) {
  __shared__ float t[32][33];
  int bx = blockIdx.x, by = blockIdx.y, bz = blockIdx.z;
  const float* ip = in + (size_t)bz * in_bs + (size_t)(bx * 32) * C + by * 32;
  bf16* op = out + (size_t)bz * out_bs + (size_t)(by * 32) * R + bx * 32;
  int x = threadIdx.x & 31, y = threadIdx.x >> 5;
#pragma unroll
  for (int yy = 0; yy < 32; yy += 8)
    t[y + yy][x] = ip[(size_t)(y + yy) * C + x];
  __syncthreads();
#pragma unroll
  for (int yy = 0; yy < 32; yy += 8)
    op[(size_t)(y + yy) * R + x] = (bf16)t[x][y + yy];
}

// ------------------------------------------------- transpose V (bf16->bf16)
__global__ __launch_bounds__(256)
void transpose_v(const bf16* __restrict__ v, bf16* __restrict__ vT) {
  __shared__ bf16 t[64][72];
  int st = blockIdx.x;
  int bh = blockIdx.y;
  const bf16* ip = v + ((size_t)bh * NS + st * 64) * NDK;
  bf16* op = vT + (size_t)bh * NDK * NS + st * 64;
  int tid = threadIdx.x;
#pragma unroll
  for (int c = tid; c < 512; c += 256) {
    int r = c >> 3, q = c & 7;
    bf16x8 d = *(const bf16x8*)&ip[(size_t)r * NDK + q * 8];
#pragma unroll
    for (int j = 0; j < 8; j++) t[r][q * 8 + j] = d[j];
  }
  __syncthreads();
#pragma unroll
  for (int c = tid; c < 512; c += 256) {
    int dv = c >> 3, sq = c & 7;
    bf16x8 d;
#pragma unroll
    for (int j = 0; j < 8; j++) d[j] = t[sq * 8 + j][dv];
    *(bf16x8*)&op[(size_t)dv * NS + sq * 8] = d;
  }
}

// ---------------------------------------------------------------- GEMM
template<int EPI>
__global__ __launch_bounds__(256)
void gemm_bt(const bf16* __restrict__ A, const bf16* __restrict__ Bt,
             const float* __restrict__ bias0, const float* __restrict__ bias1,
             const float* __restrict__ bias2, void* __restrict__ out0,
             int M, int N, int K) {
  __shared__ __align__(16) bf16 lA[128 * 32];
  __shared__ __align__(16) bf16 lB[128 * 32];
  const int tid = threadIdx.x;
  const int lane = tid & 63;
  const int w = tid >> 6;
  const int wr = w >> 1, wc = w & 1;
  const int blane = lane & 15, glane = lane >> 4;
  const int bm = blockIdx.x * 128;
  const int bn = blockIdx.y * 128;

  f32x4 acc[4][4] = {};
  const bf16* aBase = A + (size_t)bm * K;
  const bf16* bBase = Bt + (size_t)bn * K;
  const int c0 = tid, c1 = tid + 256;

  for (int kt = 0; kt < K; kt += 32) {
    const bf16* ag = aBase + kt;
    const bf16* bg = bBase + kt;
    load_lds16(ag + (size_t)(c0 >> 2) * K + (c0 & 3) * 8, &lA[c0 * 8]);
    load_lds16(ag + (size_t)(c1 >> 2) * K + (c1 & 3) * 8, &lA[c1 * 8]);
    load_lds16(bg + (size_t)(c0 >> 2) * K + (c0 & 3) * 8, &lB[c0 * 8]);
    load_lds16(bg + (size_t)(c1 >> 2) * K + (c1 & 3) * 8, &lB[c1 * 8]);
    __syncthreads();
    bf16x8 af[4], bfr[4];
#pragma unroll
    for (int m = 0; m < 4; m++) {
      int row = wr * 64 + m * 16 + blane;
      af[m] = *(const bf16x8*)&lA[row * 32 + glane * 8];
    }
#pragma unroll
    for (int n = 0; n < 4; n++) {
      int row = wc * 64 + n * 16 + blane;
      bfr[n] = *(const bf16x8*)&lB[row * 32 + glane * 8];
    }
#pragma unroll
    for (int m = 0; m < 4; m++)
#pragma unroll
      for (int n = 0; n < 4; n++)
        acc[m][n] = __builtin_amdgcn_mfma_f32_16x16x32_bf16(af[m], bfr[n], acc[m][n], 0, 0, 0);
    __syncthreads();
  }

#pragma unroll
  for (int m = 0; m < 4; m++) {
#pragma unroll
    for (int n = 0; n < 4; n++) {
      int col = bn + wc * 64 + n * 16 + blane;
      if (EPI == 0) {
        int sel = col >> 10;
        int hh = (col & 1023) >> 6;
        int dv = col & 63;
        const float* bp = (sel == 0) ? bias0 : (sel == 1) ? bias1 : bias2;
        float bias = bp[col & 1023];
        bf16* outb = (bf16*)out0 + (size_t)sel * NB * NH * NS * NDK;
#pragma unroll
        for (int i = 0; i < 4; i++) {
          int row = bm + wr * 64 + m * 16 + glane * 4 + i;
          int b_ = row >> 11, s_ = row & 2047;
          outb[(((size_t)(b_ * NH + hh) * NS + s_) * NDK) + dv] = (bf16)(acc[m][n][i] + bias);
        }
      } else if (EPI == 1) {
        float bias = bias0[col];
#pragma unroll
        for (int i = 0; i < 4; i++) {
          int row = bm + wr * 64 + m * 16 + glane * 4 + i;
          float v = acc[m][n][i] + bias;
          v = v > 0.f ? v : 0.f;
          ((bf16*)out0)[(size_t)row * N + col] = (bf16)v;
        }
      } else {
        float bias = bias0[col];
#pragma unroll
        for (int i = 0; i < 4; i++) {
          int row = bm + wr * 64 + m * 16 + glane * 4 + i;
          ((float*)out0)[(size_t)row * N + col] = acc[m][n][i] + bias;
        }
      }
    }
  }
}

// ---------------------------------------------------------------- flash attn v3
// 4 waves x 32 q-rows (QBLK=128), KVBLK=64, swapped 32x32x16 MFMA, in-register
// softmax, permlane32_swap cross-half exchange, defer-max, setprio.
__global__ __launch_bounds__(256)
void flash_attn3(const bf16* __restrict__ q, const bf16* __restrict__ k,
                 const bf16* __restrict__ vT, bf16* __restrict__ o) {
  __shared__ __align__(16) bf16 lK[2][64 * 64];
  __shared__ __align__(16) bf16 lV[2][64 * 64];
  const int tid = threadIdx.x, lane = tid & 63, w = tid >> 6;
  const int ql = lane & 31, hi = lane >> 5;
  const int bh = blockIdx.y, qt = blockIdx.x;
  const size_t hb = (size_t)bh * NS * NDK;
  const int qrow = qt * 128 + w * 32 + ql;

  // Q fragments: B-operand, col=q (lane-local), k = d = 16*ks + 8*hi + j
  bf16x8 qf[4];
#pragma unroll
  for (int ks = 0; ks < 4; ks++)
    qf[ks] = *(const bf16x8*)&q[hb + (size_t)qrow * NDK + ks * 16 + hi * 8];

  // staging: 512 chunks of 16B per tile; thread handles chunks tid and tid+256.
  const int r0 = tid >> 3, s0 = ((tid & 7) ^ (r0 & 7)) * 8;
  const int r1 = r0 + 32, s1 = ((tid & 7) ^ (r1 & 7)) * 8;
  const bf16* k0 = k + hb + (size_t)r0 * NDK + s0;
  const bf16* k1 = k + hb + (size_t)r1 * NDK + s1;
  const bf16* v0 = vT + hb + (size_t)r0 * NS + s0;
  const bf16* v1 = vT + hb + (size_t)r1 * NS + s1;

  f32x16 o0 = {}, o1 = {};
  float mR = -3e38f, lR = 0.f;
  const float cl2 = 0.18033688f;  // (1/sqrt(64)) * log2(e)

  // stage tile 0 into buf 0
  load_lds16(k0, &lK[0][tid * 8]);
  load_lds16(k1, &lK[0][(tid + 256) * 8]);
  load_lds16(v0, &lV[0][tid * 8]);
  load_lds16(v1, &lV[0][(tid + 256) * 8]);
  __syncthreads();

  const char* lKc = (const char*)&lK[0][0];
  const char* lVc = (const char*)&lV[0][0];
  const int swz = (ql & 7) << 4;

  for (int t = 0; t < NS / 64; t++) {
    const int cur = t & 1;
    if (t < NS / 64 - 1) {
      const size_t ko = (size_t)(t + 1) * 64 * NDK;
      const int vo = (t + 1) * 64;
      load_lds16(k0 + ko, &lK[cur ^ 1][tid * 8]);
      load_lds16(k1 + ko, &lK[cur ^ 1][(tid + 256) * 8]);
      load_lds16(v0 + vo, &lV[cur ^ 1][tid * 8]);
      load_lds16(v1 + vo, &lV[cur ^ 1][(tid + 256) * 8]);
    }
    const char* Kb = lKc + cur * 8192;
    const char* Vb = lVc + cur * 8192;

    // ---- S^T = K * Q^T
    f32x16 st0 = {}, st1 = {};
    __builtin_amdgcn_s_setprio(1);
#pragma unroll
    for (int ks = 0; ks < 4; ks++) {
      int byt = (32 * ks + 16 * hi) ^ swz;
      bf16x8 kf0 = *(const bf16x8*)(Kb + ql * 128 + byt);
      bf16x8 kf1 = *(const bf16x8*)(Kb + (32 + ql) * 128 + byt);
      st0 = __builtin_amdgcn_mfma_f32_32x32x16_bf16(kf0, qf[ks], st0, 0, 0, 0);
      st1 = __builtin_amdgcn_mfma_f32_32x32x16_bf16(kf1, qf[ks], st1, 0, 0, 0);
    }
    __builtin_amdgcn_s_setprio(0);

    // ---- tile max (in-register + one permlane swap)
    float mx = st0[0];
#pragma unroll
    for (int r = 1; r < 16; r++) mx = fmaxf(mx, st0[r]);
#pragma unroll
    for (int r = 0; r < 16; r++) mx = fmaxf(mx, st1[r]);
    {
      i32x2 xr = pswap((u32)__float_as_int(mx), (u32)__float_as_int(mx));
      float prt = __int_as_float(hi ? xr[0] : xr[1]);
      mx = fmaxf(mx, prt);
    }

    // ---- defer-max: only rescale when the max moved materially
    if (!__all((mx - mR) * cl2 <= 8.0f)) {
      float mn = fmaxf(mR, mx);
      float al = exp2f((mR - mn) * cl2);
      lR *= al;
#pragma unroll
      for (int r = 0; r < 16; r++) { o0[r] *= al; o1[r] *= al; }
      mR = mn;
    }
    float cmn = mR * cl2;
    float ls = 0.f;
#pragma unroll
    for (int r = 0; r < 16; r++) { float p = exp2f(fmaf(st0[r], cl2, -cmn)); st0[r] = p; ls += p; }
#pragma unroll
    for (int r = 0; r < 16; r++) { float p = exp2f(fmaf(st1[r], cl2, -cmn)); st1[r] = p; ls += p; }
    {
      i32x2 sr = pswap((u32)__float_as_int(ls), (u32)__float_as_int(ls));
      float lsp = __int_as_float(hi ? sr[0] : sr[1]);
      float lo_ = hi ? lsp : ls, hi_ = hi ? ls : lsp;
      lR += lo_ + hi_;   // fixed order: identical in both halves
    }

    // ---- P -> bf16 B-fragments via permlane32_swap + PV
#pragma unroll
    for (int tt = 0; tt < 2; tt++) {
      f32x16 stv = (tt == 0) ? st0 : st1;
      u32 wv[8];
#pragma unroll
      for (int i = 0; i < 8; i++) wv[i] = pack2(stv[2 * i], stv[2 * i + 1]);
#pragma unroll
      for (int kk = 0; kk < 2; kk++) {
        const int base = 4 * kk;
        i32x2 e0 = pswap(wv[base + 0], wv[base + 2]);
        i32x2 e1 = pswap(wv[base + 1], wv[base + 3]);
        union { u32 u[4]; bf16x8 v; } pf;
        pf.u[0] = (u32)e0[0];
        pf.u[1] = (u32)e1[0];
        pf.u[2] = (u32)e0[1];
        pf.u[3] = (u32)e1[1];
        const int ks = 2 * tt + kk;
        int vbyt = (32 * ks + 16 * hi) ^ swz;
        bf16x8 vf0 = *(const bf16x8*)(Vb + ql * 128 + vbyt);
        bf16x8 vf1 = *(const bf16x8*)(Vb + (32 + ql) * 128 + vbyt);
        __builtin_amdgcn_s_setprio(1);
        o0 = __builtin_amdgcn_mfma_f32_32x32x16_bf16(vf0, pf.v, o0, 0, 0, 0);
        o1 = __builtin_amdgcn_mfma_f32_32x32x16_bf16(vf1, pf.v, o1, 0, 0, 0);
        __builtin_amdgcn_s_setprio(0);
      }
    }
    __syncthreads();
  }

  // ---- epilogue
  float invl = 1.0f / lR;
  int b_ = bh >> 4, h_ = bh & 15;
  bf16* ob = o + ((size_t)(b_ * NS + qrow) * (NH * NDK)) + h_ * NDK;
#pragma unroll
  for (int rp = 0; rp < 8; rp++) {
    int dv = 8 * (rp >> 1) + 2 * (rp & 1) + 4 * hi;
    *(u32*)&ob[dv]      = pack2(o0[2 * rp] * invl, o0[2 * rp + 1] * invl);
    *(u32*)&ob[dv + 32] = pack2(o1[2 * rp] * invl, o1[2 * rp + 1] * invl);
  }
}

// ---------------------------------------------------------------- LN(residual)
template<int WB>
__global__ __launch_bounds__(256)
void ln_res(const float* __restrict__ a, const float* __restrict__ b,
            const float* __restrict__ g, const float* __restrict__ be,
            float* __restrict__ y, bf16* __restrict__ yb) {
  int row = blockIdx.x;
  int tid = threadIdx.x;
  const float4* a4 = (const float4*)(a + (size_t)row * ND);
  const float4* b4 = (const float4*)(b + (size_t)row * ND);
  float4 av = a4[tid], bv = b4[tid];
  float x0 = av.x + bv.x, x1 = av.y + bv.y, x2 = av.z + bv.z, x3 = av.w + bv.w;
  float s = x0 + x1 + x2 + x3;
  float qq_ = x0 * x0 + x1 * x1 + x2 * x2 + x3 * x3;
#pragma unroll
  for (int d = 1; d < 64; d <<= 1) { s += __shfl_xor(s, d); qq_ += __shfl_xor(qq_, d); }
  __shared__ float ss[4], sq[4];
  int w = tid >> 6, lane = tid & 63;
  if (lane == 0) { ss[w] = s; sq[w] = qq_; }
  __syncthreads();
  s = ss[0] + ss[1] + ss[2] + ss[3];
  qq_ = sq[0] + sq[1] + sq[2] + sq[3];
  float mu = s * (1.0f / ND);
  float var = qq_ * (1.0f / ND) - mu * mu;
  float rs = 1.0f / sqrtf(var + 1e-5f);
  const float4* g4 = (const float4*)g;
  const float4* e4 = (const float4*)be;
  float4 gv = g4[tid], ev = e4[tid];
  float o0 = (x0 - mu) * rs * gv.x + ev.x;
  float o1 = (x1 - mu) * rs * gv.y + ev.y;
  float o2 = (x2 - mu) * rs * gv.z + ev.z;
  float o3 = (x3 - mu) * rs * gv.w + ev.w;
  float4 ov = {o0, o1, o2, o3};
  *(float4*)(y + (size_t)row * ND + tid * 4) = ov;
  if (WB) {
    bf16x4 wv;
    wv[0] = (bf16)o0; wv[1] = (bf16)o1; wv[2] = (bf16)o2; wv[3] = (bf16)o3;
    *(bf16x4*)&yb[(size_t)row * ND + tid * 4] = wv;
  }
}

// ---------------------------------------------------------------- launch
extern "C" void kernel_launch(void* const* d_in, const int* in_sizes, int n_in,
                              void* d_out, int out_size, void* d_ws, size_t ws_size,
                              hipStream_t stream) {
  const float* src = (const float*)d_in[0];
  const float* wq  = (const float*)d_in[1];
  const float* bq  = (const float*)d_in[2];
  const float* wk  = (const float*)d_in[3];
  const float* bk  = (const float*)d_in[4];
  const float* wv  = (const float*)d_in[5];
  const float* bv  = (const float*)d_in[6];
  const float* wo  = (const float*)d_in[7];
  const float* bo  = (const float*)d_in[8];
  const float* g1  = (const float*)d_in[9];
  const float* be1 = (const float*)d_in[10];
  const float* w1  = (const float*)d_in[11];
  const float* b1  = (const float*)d_in[12];
  const float* w2  = (const float*)d_in[13];
  const float* b2  = (const float*)d_in[14];
  const float* g2  = (const float*)d_in[15];
  const float* be2 = (const float*)d_in[16];

  char* ws = (char*)d_ws;
  bf16*  srcb  = (bf16*)(ws + 0);            // 16 MiB
  bf16*  wqkvT = (bf16*)(ws + 16777216);     // 6 MiB  [3072][1024]
  bf16*  woT   = (bf16*)(ws + 23068672);     // 2 MiB  [1024][1024]
  bf16*  w1T   = (bf16*)(ws + 25165824);     // 8 MiB  [4096][1024]
  bf16*  w2T   = (bf16*)(ws + 33554432);     // 8 MiB  [1024][4096]
  bf16*  qkv   = (bf16*)(ws + 41943040);     // 48 MiB q|k|v [BH][S][DK]
  bf16*  vT    = (bf16*)(ws + 92274688);     // 16 MiB [BH][DK][S]
  bf16*  attno = (bf16*)(ws + 109051904);    // 16 MiB [B][S][H*DK]
  float* tmpf  = (float*)(ws + 125829120);   // 32 MiB attn_out / ff
  float* x     = (float*)(ws + 159383552);   // 32 MiB
  bf16*  xb    = (bf16*)(ws + 192937984);    // 16 MiB
  bf16*  hbuf  = qkv;                         // 64 MiB alias (qkv+vT dead after attn)

  const size_t QKVSZ = (size_t)NB * NH * NS * NDK;

  cvt_f32_bf16<<<8192, 256, 0, stream>>>(src, srcb, NM * ND);
  transpose_cvt<<<dim3(32, 2, 16), 256, 0, stream>>>(wq, wqkvT,               1024, 64, 65536, 65536);
  transpose_cvt<<<dim3(32, 2, 16), 256, 0, stream>>>(wk, wqkvT + 1024 * 1024, 1024, 64, 65536, 65536);
  transpose_cvt<<<dim3(32, 2, 16), 256, 0, stream>>>(wv, wqkvT + 2048 * 1024, 1024, 64, 65536, 65536);
  transpose_cvt<<<dim3(32, 32, 1), 256, 0, stream>>>(wo, woT, 1024, 1024, 0, 0);
  transpose_cvt<<<dim3(32, 128, 1), 256, 0, stream>>>(w1, w1T, 1024, 4096, 0, 0);
  transpose_cvt<<<dim3(128, 32, 1), 256, 0, stream>>>(w2, w2T, 4096, 1024, 0, 0);

  gemm_bt<0><<<dim3(64, 24), 256, 0, stream>>>(srcb, wqkvT, bq, bk, bv, qkv, NM, 3072, 1024);
  transpose_v<<<dim3(32, 64), 256, 0, stream>>>(qkv + 2 * QKVSZ, vT);
  flash_attn3<<<dim3(16, 64), 256, 0, stream>>>(qkv, qkv + QKVSZ, vT, attno);
  gemm_bt<2><<<dim3(64, 8), 256, 0, stream>>>(attno, woT, bo, nullptr, nullptr, tmpf, NM, 1024, 1024);
  ln_res<1><<<8192, 256, 0, stream>>>(src, tmpf, g1, be1, x, xb);
  gemm_bt<1><<<dim3(64, 32), 256, 0, stream>>>(xb, w1T, b1, nullptr, nullptr, hbuf, NM, 4096, 1024);
  gemm_bt<2><<<dim3(64, 8), 256, 0, stream>>>(hbuf, w2T, b2, nullptr, nullptr, tmpf, NM, 1024, 4096);
  ln_res<0><<<8192, 256, 0, stream>>>(x, tmpf, g2, be2, (float*)d_out, nullptr);
}

// Round 4
// 496.281 us; speedup vs baseline: 1.1914x; 1.0548x over previous
//
#include <hip/hip_runtime.h>

typedef __bf16 bf16;
typedef __bf16 bf16x8 __attribute__((ext_vector_type(8)));
typedef __bf16 bf16x4 __attribute__((ext_vector_type(4)));
typedef float  f32x4  __attribute__((ext_vector_type(4)));
typedef float  f32x16 __attribute__((ext_vector_type(16)));
typedef unsigned int u32;
typedef int i32x2 __attribute__((ext_vector_type(2)));

#define NB 4
#define NS 2048
#define ND 1024
#define NH 16
#define NDK 64
#define NFF 4096
#define NM (NB*NS)   // 8192 rows

__device__ __forceinline__ void load_lds16(const void* g, void* l) {
  __builtin_amdgcn_global_load_lds(
      (const __attribute__((address_space(1))) void*)g,
      (__attribute__((address_space(3))) void*)l, 16, 0, 0);
}

__device__ __forceinline__ u32 pack2(float a, float b) {
  union { bf16 h[2]; u32 u; } z;
  z.h[0] = (bf16)a; z.h[1] = (bf16)b;
  return z.u;
}

__device__ __forceinline__ i32x2 pswap(u32 a, u32 b) {
#if __has_builtin(__builtin_amdgcn_permlane32_swap)
  return __builtin_amdgcn_permlane32_swap((int)a, (int)b, false, false);
#else
  u32 x = a, y = b;
  asm volatile("v_permlane32_swap_b32 %0, %1" : "+v"(x), "+v"(y));
  i32x2 r; r[0] = (int)x; r[1] = (int)y; return r;
#endif
}

// ---------------------------------------------------------------- cvt src
__global__ __launch_bounds__(256)
void cvt_f32_bf16(const float* __restrict__ in, bf16* __restrict__ out, int n) {
  int i = (blockIdx.x * 256 + threadIdx.x) * 4;
  if (i < n) {
    float4 v = *(const float4*)&in[i];
    bf16x4 o;
    o[0] = (bf16)v.x; o[1] = (bf16)v.y; o[2] = (bf16)v.z; o[3] = (bf16)v.w;
    *(bf16x4*)&out[i] = o;
  }
}

// ------------------------------------------------- transpose fp32 -> bf16^T
__global__ __launch_bounds__(256)
void transpose_cvt(const float* __restrict__ in, bf16* __restrict__ out,
                   int R, int C, size_t in_bs, size_t out_bs) {
  __shared__ float t[32][33];
  int bx = blockIdx.x, by = blockIdx.y, bz = blockIdx.z;
  const float* ip = in + (size_t)bz * in_bs + (size_t)(bx * 32) * C + by * 32;
  bf16* op = out + (size_t)bz * out_bs + (size_t)(by * 32) * R + bx * 32;
  int x = threadIdx.x & 31, y = threadIdx.x >> 5;
#pragma unroll
  for (int yy = 0; yy < 32; yy += 8)
    t[y + yy][x] = ip[(size_t)(y + yy) * C + x];
  __syncthreads();
#pragma unroll
  for (int yy = 0; yy < 32; yy += 8)
    op[(size_t)(y + yy) * R + x] = (bf16)t[x][y + yy];
}

// ------------------------------------------------- transpose V (bf16->bf16)
__global__ __launch_bounds__(256)
void transpose_v(const bf16* __restrict__ v, bf16* __restrict__ vT) {
  __shared__ bf16 t[64][72];
  int st = blockIdx.x;
  int bh = blockIdx.y;
  const bf16* ip = v + ((size_t)bh * NS + st * 64) * NDK;
  bf16* op = vT + (size_t)bh * NDK * NS + st * 64;
  int tid = threadIdx.x;
#pragma unroll
  for (int c = tid; c < 512; c += 256) {
    int r = c >> 3, q = c & 7;
    bf16x8 d = *(const bf16x8*)&ip[(size_t)r * NDK + q * 8];
#pragma unroll
    for (int j = 0; j < 8; j++) t[r][q * 8 + j] = d[j];
  }
  __syncthreads();
#pragma unroll
  for (int c = tid; c < 512; c += 256) {
    int dv = c >> 3, sq = c & 7;
    bf16x8 d;
#pragma unroll
    for (int j = 0; j < 8; j++) d[j] = t[sq * 8 + j][dv];
    *(bf16x8*)&op[(size_t)dv * NS + sq * 8] = d;
  }
}

// ---------------------------------------------------------------- GEMM 8-phase
// C[M,N] = A[M,K] * Bt[N,K]^T. BM=256, BK=64, 512 threads (8 waves, 2Mx4N).
// T2 swizzle (pre-swizzled global src + XOR read), T3/T4 counted vmcnt, T5 setprio.
// EPI 0: QKV scatter; EPI 1: bf16+relu; EPI 2: f32+bias.
#define BAR()  __builtin_amdgcn_s_barrier()
#define LGKM0() do { asm volatile("s_waitcnt lgkmcnt(0)" ::: "memory"); \
                     __builtin_amdgcn_sched_barrier(0); } while (0)

template<int BN, int EPI>
__global__ __launch_bounds__(512, 2)
void gemm8p(const bf16* __restrict__ A, const bf16* __restrict__ Bt,
            const float* __restrict__ bias0, const float* __restrict__ bias1,
            const float* __restrict__ bias2, void* __restrict__ out0,
            int M, int N, int K) {
  constexpr int NFR = BN / 64;          // n-frags per wave (4 or 2)
  __shared__ __align__(16) bf16 lA[2][256 * 64];
  __shared__ __align__(16) bf16 lB[2][BN * 64];

  const int tid = threadIdx.x, lane = tid & 63, w = tid >> 6;
  const int wr = w >> 2, wn = w & 3;
  const int blane = lane & 15, glane = lane >> 4;

  // bijective XCD swizzle (nwg % 8 == 0 for all launches)
  const int nwg = gridDim.x;
  const int cpx = nwg >> 3;
  const int bid = blockIdx.x;
  const int swzb = (bid & 7) * cpx + (bid >> 3);
  const int gridM = M >> 8;
  const int bm = (swzb % gridM) * 256;
  const int bn = (swzb / gridM) * BN;

  f32x4 acc[8][NFR] = {};
  bf16x8 aF[8], bF[2 * NFR];

  auto stageA = [&](int kt, int h, int b) {
#pragma unroll
    for (int j = 0; j < 2; j++) {
      int ch = w * 128 + j * 64 + lane;
      int r = h * 128 + (ch >> 3), s = ch & 7;
      load_lds16(A + (size_t)(bm + r) * K + kt * 64 + ((s ^ (r & 7)) * 8),
                 &lA[b][(h * 1024 + ch) * 8]);
    }
  };
  auto stageB = [&](int kt, int h, int b) {
    if constexpr (BN == 256) {
#pragma unroll
      for (int j = 0; j < 2; j++) {
        int ch = w * 128 + j * 64 + lane;
        int r = h * 128 + (ch >> 3), s = ch & 7;
        load_lds16(Bt + (size_t)(bn + r) * K + kt * 64 + ((s ^ (r & 7)) * 8),
                   &lB[b][(h * 1024 + ch) * 8]);
      }
    } else {
      int ch = w * 64 + lane;
      int r = h * 64 + (ch >> 3), s = ch & 7;
      load_lds16(Bt + (size_t)(bn + r) * K + kt * 64 + ((s ^ (r & 7)) * 8),
                 &lB[b][(h * 512 + ch) * 8]);
    }
  };
  auto vmwait = [&]() {
    if constexpr (BN == 256) asm volatile("s_waitcnt vmcnt(6)" ::: "memory");
    else                     asm volatile("s_waitcnt vmcnt(4)" ::: "memory");
  };
  auto ldA = [&](int mh, int b) {
#pragma unroll
    for (int mf = 0; mf < 4; mf++)
#pragma unroll
      for (int ks = 0; ks < 2; ks++) {
        int r = wr * 128 + mh * 64 + mf * 16 + blane;
        int s = (ks * 4 + glane) ^ (r & 7);
        aF[mf * 2 + ks] = *(const bf16x8*)&lA[b][r * 64 + s * 8];
      }
  };
  auto ldB = [&](int b) {
#pragma unroll
    for (int nf = 0; nf < NFR; nf++)
#pragma unroll
      for (int ks = 0; ks < 2; ks++) {
        int r = wn * (NFR * 16) + nf * 16 + blane;
        int s = (ks * 4 + glane) ^ (r & 7);
        bF[nf * 2 + ks] = *(const bf16x8*)&lB[b][r * 64 + s * 8];
      }
  };

#define MMAQ(mh, nh)  do {                                                  \
    __builtin_amdgcn_s_setprio(1);                                          \
    _Pragma("unroll")                                                       \
    for (int mf = 0; mf < 4; mf++)                                          \
      _Pragma("unroll")                                                     \
      for (int nq = 0; nq < NFR / 2; nq++)                                  \
        _Pragma("unroll")                                                   \
        for (int ks = 0; ks < 2; ks++)                                      \
          acc[(mh) * 4 + mf][(nh) * (NFR / 2) + nq] =                       \
            __builtin_amdgcn_mfma_f32_16x16x32_bf16(                        \
              aF[mf * 2 + ks], bF[((nh) * (NFR / 2) + nq) * 2 + ks],        \
              acc[(mh) * 4 + mf][(nh) * (NFR / 2) + nq], 0, 0, 0);          \
    __builtin_amdgcn_s_setprio(0);                                          \
  } while (0)

  // ---- prologue: tile0 full + tile1 {B0,B1,A0}
  stageB(0, 0, 0); stageB(0, 1, 0); stageA(0, 0, 0); stageA(0, 1, 0);
  stageB(1, 0, 1); stageB(1, 1, 1); stageA(1, 0, 1);
  vmwait();
  BAR();

  const int NT = K >> 6;
  for (int u = 0; u < NT; u += 2) {
    const int t2 = (u + 2 < NT) ? u + 2 : u;       // clamped sources (parity kept)
    const int t3 = (u + 3 < NT) ? u + 3 : u + 1;
    // P1
    ldA(0, 0); ldB(0);
    stageA(u + 1, 1, 1);
    BAR(); LGKM0(); MMAQ(0, 0); BAR();
    // P2
    stageB(t2, 0, 0);
    BAR(); MMAQ(0, 1); BAR();
    // P3
    ldA(1, 0);
    stageB(t2, 1, 0);
    BAR(); LGKM0(); MMAQ(1, 1); BAR();
    // P4
    stageA(t2, 0, 0);
    BAR(); MMAQ(1, 0); vmwait(); BAR();
    // P5
    ldA(0, 1); ldB(1);
    stageA(t2, 1, 0);
    BAR(); LGKM0(); MMAQ(0, 0); BAR();
    // P6
    stageB(t3, 0, 1);
    BAR(); MMAQ(0, 1); BAR();
    // P7
    ldA(1, 1);
    stageB(t3, 1, 1);
    BAR(); LGKM0(); MMAQ(1, 1); BAR();
    // P8
    stageA(t3, 0, 1);
    BAR(); MMAQ(1, 0); vmwait(); BAR();
  }

  // ---- epilogue
#pragma unroll
  for (int am = 0; am < 8; am++) {
#pragma unroll
    for (int nf = 0; nf < NFR; nf++) {
      int col = bn + wn * (NFR * 16) + nf * 16 + blane;
      int rowb = bm + wr * 128 + (am >> 2) * 64 + (am & 3) * 16 + glane * 4;
      if (EPI == 0) {
        int sel = col >> 10;
        int hh = (col & 1023) >> 6;
        int dv = col & 63;
        const float* bp = (sel == 0) ? bias0 : (sel == 1) ? bias1 : bias2;
        float bias = bp[col & 1023];
        bf16* outb = (bf16*)out0 + (size_t)sel * NB * NH * NS * NDK;
#pragma unroll
        for (int i = 0; i < 4; i++) {
          int row = rowb + i;
          int b_ = row >> 11, s_ = row & 2047;
          outb[(((size_t)(b_ * NH + hh) * NS + s_) * NDK) + dv] = (bf16)(acc[am][nf][i] + bias);
        }
      } else if (EPI == 1) {
        float bias = bias0[col];
#pragma unroll
        for (int i = 0; i < 4; i++) {
          float v = acc[am][nf][i] + bias;
          v = v > 0.f ? v : 0.f;
          ((bf16*)out0)[(size_t)(rowb + i) * N + col] = (bf16)v;
        }
      } else {
        float bias = bias0[col];
#pragma unroll
        for (int i = 0; i < 4; i++)
          ((float*)out0)[(size_t)(rowb + i) * N + col] = acc[am][nf][i] + bias;
      }
    }
  }
#undef MMAQ
}

// ---------------------------------------------------------------- flash attn v3
__global__ __launch_bounds__(256)
void flash_attn3(const bf16* __restrict__ q, const bf16* __restrict__ k,
                 const bf16* __restrict__ vT, bf16* __restrict__ o) {
  __shared__ __align__(16) bf16 lK[2][64 * 64];
  __shared__ __align__(16) bf16 lV[2][64 * 64];
  const int tid = threadIdx.x, lane = tid & 63, w = tid >> 6;
  const int ql = lane & 31, hi = lane >> 5;
  const int bh = blockIdx.y, qt = blockIdx.x;
  const size_t hb = (size_t)bh * NS * NDK;
  const int qrow = qt * 128 + w * 32 + ql;

  bf16x8 qf[4];
#pragma unroll
  for (int ks = 0; ks < 4; ks++)
    qf[ks] = *(const bf16x8*)&q[hb + (size_t)qrow * NDK + ks * 16 + hi * 8];

  const int r0 = tid >> 3, s0 = ((tid & 7) ^ (r0 & 7)) * 8;
  const int r1 = r0 + 32, s1 = ((tid & 7) ^ (r1 & 7)) * 8;
  const bf16* k0 = k + hb + (size_t)r0 * NDK + s0;
  const bf16* k1 = k + hb + (size_t)r1 * NDK + s1;
  const bf16* v0 = vT + hb + (size_t)r0 * NS + s0;
  const bf16* v1 = vT + hb + (size_t)r1 * NS + s1;

  f32x16 o0 = {}, o1 = {};
  float mR = -3e38f, lR = 0.f;
  const float cl2 = 0.18033688f;

  load_lds16(k0, &lK[0][tid * 8]);
  load_lds16(k1, &lK[0][(tid + 256) * 8]);
  load_lds16(v0, &lV[0][tid * 8]);
  load_lds16(v1, &lV[0][(tid + 256) * 8]);
  __syncthreads();

  const char* lKc = (const char*)&lK[0][0];
  const char* lVc = (const char*)&lV[0][0];
  const int swz = (ql & 7) << 4;

  for (int t = 0; t < NS / 64; t++) {
    const int cur = t & 1;
    if (t < NS / 64 - 1) {
      const size_t ko = (size_t)(t + 1) * 64 * NDK;
      const int vo = (t + 1) * 64;
      load_lds16(k0 + ko, &lK[cur ^ 1][tid * 8]);
      load_lds16(k1 + ko, &lK[cur ^ 1][(tid + 256) * 8]);
      load_lds16(v0 + vo, &lV[cur ^ 1][tid * 8]);
      load_lds16(v1 + vo, &lV[cur ^ 1][(tid + 256) * 8]);
    }
    const char* Kb = lKc + cur * 8192;
    const char* Vb = lVc + cur * 8192;

    f32x16 st0 = {}, st1 = {};
    __builtin_amdgcn_s_setprio(1);
#pragma unroll
    for (int ks = 0; ks < 4; ks++) {
      int byt = (32 * ks + 16 * hi) ^ swz;
      bf16x8 kf0 = *(const bf16x8*)(Kb + ql * 128 + byt);
      bf16x8 kf1 = *(const bf16x8*)(Kb + (32 + ql) * 128 + byt);
      st0 = __builtin_amdgcn_mfma_f32_32x32x16_bf16(kf0, qf[ks], st0, 0, 0, 0);
      st1 = __builtin_amdgcn_mfma_f32_32x32x16_bf16(kf1, qf[ks], st1, 0, 0, 0);
    }
    __builtin_amdgcn_s_setprio(0);

    float mx = st0[0];
#pragma unroll
    for (int r = 1; r < 16; r++) mx = fmaxf(mx, st0[r]);
#pragma unroll
    for (int r = 0; r < 16; r++) mx = fmaxf(mx, st1[r]);
    {
      i32x2 xr = pswap((u32)__float_as_int(mx), (u32)__float_as_int(mx));
      float prt = __int_as_float(hi ? xr[0] : xr[1]);
      mx = fmaxf(mx, prt);
    }

    if (!__all((mx - mR) * cl2 <= 8.0f)) {
      float mn = fmaxf(mR, mx);
      float al = exp2f((mR - mn) * cl2);
      lR *= al;
#pragma unroll
      for (int r = 0; r < 16; r++) { o0[r] *= al; o1[r] *= al; }
      mR = mn;
    }
    float cmn = mR * cl2;
    float ls = 0.f;
#pragma unroll
    for (int r = 0; r < 16; r++) { float p = exp2f(fmaf(st0[r], cl2, -cmn)); st0[r] = p; ls += p; }
#pragma unroll
    for (int r = 0; r < 16; r++) { float p = exp2f(fmaf(st1[r], cl2, -cmn)); st1[r] = p; ls += p; }
    {
      i32x2 sr = pswap((u32)__float_as_int(ls), (u32)__float_as_int(ls));
      float lsp = __int_as_float(hi ? sr[0] : sr[1]);
      float lo_ = hi ? lsp : ls, hi_ = hi ? ls : lsp;
      lR += lo_ + hi_;
    }

#pragma unroll
    for (int tt = 0; tt < 2; tt++) {
      f32x16 stv = (tt == 0) ? st0 : st1;
      u32 wv[8];
#pragma unroll
      for (int i = 0; i < 8; i++) wv[i] = pack2(stv[2 * i], stv[2 * i + 1]);
#pragma unroll
      for (int kk = 0; kk < 2; kk++) {
        const int base = 4 * kk;
        i32x2 e0 = pswap(wv[base + 0], wv[base + 2]);
        i32x2 e1 = pswap(wv[base + 1], wv[base + 3]);
        union { u32 u[4]; bf16x8 v; } pf;
        pf.u[0] = (u32)e0[0];
        pf.u[1] = (u32)e1[0];
        pf.u[2] = (u32)e0[1];
        pf.u[3] = (u32)e1[1];
        const int ks = 2 * tt + kk;
        int vbyt = (32 * ks + 16 * hi) ^ swz;
        bf16x8 vf0 = *(const bf16x8*)(Vb + ql * 128 + vbyt);
        bf16x8 vf1 = *(const bf16x8*)(Vb + (32 + ql) * 128 + vbyt);
        __builtin_amdgcn_s_setprio(1);
        o0 = __builtin_amdgcn_mfma_f32_32x32x16_bf16(vf0, pf.v, o0, 0, 0, 0);
        o1 = __builtin_amdgcn_mfma_f32_32x32x16_bf16(vf1, pf.v, o1, 0, 0, 0);
        __builtin_amdgcn_s_setprio(0);
      }
    }
    __syncthreads();
  }

  float invl = 1.0f / lR;
  int b_ = bh >> 4, h_ = bh & 15;
  bf16* ob = o + ((size_t)(b_ * NS + qrow) * (NH * NDK)) + h_ * NDK;
#pragma unroll
  for (int rp = 0; rp < 8; rp++) {
    int dv = 8 * (rp >> 1) + 2 * (rp & 1) + 4 * hi;
    *(u32*)&ob[dv]      = pack2(o0[2 * rp] * invl, o0[2 * rp + 1] * invl);
    *(u32*)&ob[dv + 32] = pack2(o1[2 * rp] * invl, o1[2 * rp + 1] * invl);
  }
}

// ---------------------------------------------------------------- LN(residual)
template<int WB>
__global__ __launch_bounds__(256)
void ln_res(const float* __restrict__ a, const float* __restrict__ b,
            const float* __restrict__ g, const float* __restrict__ be,
            float* __restrict__ y, bf16* __restrict__ yb) {
  int row = blockIdx.x;
  int tid = threadIdx.x;
  const float4* a4 = (const float4*)(a + (size_t)row * ND);
  const float4* b4 = (const float4*)(b + (size_t)row * ND);
  float4 av = a4[tid], bv = b4[tid];
  float x0 = av.x + bv.x, x1 = av.y + bv.y, x2 = av.z + bv.z, x3 = av.w + bv.w;
  float s = x0 + x1 + x2 + x3;
  float qq_ = x0 * x0 + x1 * x1 + x2 * x2 + x3 * x3;
#pragma unroll
  for (int d = 1; d < 64; d <<= 1) { s += __shfl_xor(s, d); qq_ += __shfl_xor(qq_, d); }
  __shared__ float ss[4], sq[4];
  int w = tid >> 6, lane = tid & 63;
  if (lane == 0) { ss[w] = s; sq[w] = qq_; }
  __syncthreads();
  s = ss[0] + ss[1] + ss[2] + ss[3];
  qq_ = sq[0] + sq[1] + sq[2] + sq[3];
  float mu = s * (1.0f / ND);
  float var = qq_ * (1.0f / ND) - mu * mu;
  float rs = 1.0f / sqrtf(var + 1e-5f);
  const float4* g4 = (const float4*)g;
  const float4* e4 = (const float4*)be;
  float4 gv = g4[tid], ev = e4[tid];
  float o0 = (x0 - mu) * rs * gv.x + ev.x;
  float o1 = (x1 - mu) * rs * gv.y + ev.y;
  float o2 = (x2 - mu) * rs * gv.z + ev.z;
  float o3 = (x3 - mu) * rs * gv.w + ev.w;
  float4 ov = {o0, o1, o2, o3};
  *(float4*)(y + (size_t)row * ND + tid * 4) = ov;
  if (WB) {
    bf16x4 wv;
    wv[0] = (bf16)o0; wv[1] = (bf16)o1; wv[2] = (bf16)o2; wv[3] = (bf16)o3;
    *(bf16x4*)&yb[(size_t)row * ND + tid * 4] = wv;
  }
}

// ---------------------------------------------------------------- launch
extern "C" void kernel_launch(void* const* d_in, const int* in_sizes, int n_in,
                              void* d_out, int out_size, void* d_ws, size_t ws_size,
                              hipStream_t stream) {
  const float* src = (const float*)d_in[0];
  const float* wq  = (const float*)d_in[1];
  const float* bq  = (const float*)d_in[2];
  const float* wk  = (const float*)d_in[3];
  const float* bk  = (const float*)d_in[4];
  const float* wv  = (const float*)d_in[5];
  const float* bv  = (const float*)d_in[6];
  const float* wo  = (const float*)d_in[7];
  const float* bo  = (const float*)d_in[8];
  const float* g1  = (const float*)d_in[9];
  const float* be1 = (const float*)d_in[10];
  const float* w1  = (const float*)d_in[11];
  const float* b1  = (const float*)d_in[12];
  const float* w2  = (const float*)d_in[13];
  const float* b2  = (const float*)d_in[14];
  const float* g2  = (const float*)d_in[15];
  const float* be2 = (const float*)d_in[16];

  char* ws = (char*)d_ws;
  bf16*  srcb  = (bf16*)(ws + 0);            // 16 MiB
  bf16*  wqkvT = (bf16*)(ws + 16777216);     // 6 MiB  [3072][1024]
  bf16*  woT   = (bf16*)(ws + 23068672);     // 2 MiB  [1024][1024]
  bf16*  w1T   = (bf16*)(ws + 25165824);     // 8 MiB  [4096][1024]
  bf16*  w2T   = (bf16*)(ws + 33554432);     // 8 MiB  [1024][4096]
  bf16*  qkv   = (bf16*)(ws + 41943040);     // 48 MiB q|k|v [BH][S][DK]
  bf16*  vT    = (bf16*)(ws + 92274688);     // 16 MiB [BH][DK][S]
  bf16*  attno = (bf16*)(ws + 109051904);    // 16 MiB [B][S][H*DK]
  float* tmpf  = (float*)(ws + 125829120);   // 32 MiB attn_out / ff
  float* x     = (float*)(ws + 159383552);   // 32 MiB
  bf16*  xb    = (bf16*)(ws + 192937984);    // 16 MiB
  bf16*  hbuf  = qkv;                         // 64 MiB alias (qkv+vT dead after attn)

  const size_t QKVSZ = (size_t)NB * NH * NS * NDK;

  cvt_f32_bf16<<<8192, 256, 0, stream>>>(src, srcb, NM * ND);
  transpose_cvt<<<dim3(32, 2, 16), 256, 0, stream>>>(wq, wqkvT,               1024, 64, 65536, 65536);
  transpose_cvt<<<dim3(32, 2, 16), 256, 0, stream>>>(wk, wqkvT + 1024 * 1024, 1024, 64, 65536, 65536);
  transpose_cvt<<<dim3(32, 2, 16), 256, 0, stream>>>(wv, wqkvT + 2048 * 1024, 1024, 64, 65536, 65536);
  transpose_cvt<<<dim3(32, 32, 1), 256, 0, stream>>>(wo, woT, 1024, 1024, 0, 0);
  transpose_cvt<<<dim3(32, 128, 1), 256, 0, stream>>>(w1, w1T, 1024, 4096, 0, 0);
  transpose_cvt<<<dim3(128, 32, 1), 256, 0, stream>>>(w2, w2T, 4096, 1024, 0, 0);

  gemm8p<256, 0><<<384, 512, 0, stream>>>(srcb, wqkvT, bq, bk, bv, qkv, NM, 3072, 1024);
  transpose_v<<<dim3(32, 64), 256, 0, stream>>>(qkv + 2 * QKVSZ, vT);
  flash_attn3<<<dim3(16, 64), 256, 0, stream>>>(qkv, qkv + QKVSZ, vT, attno);
  gemm8p<128, 2><<<256, 512, 0, stream>>>(attno, woT, bo, nullptr, nullptr, tmpf, NM, 1024, 1024);
  ln_res<1><<<8192, 256, 0, stream>>>(src, tmpf, g1, be1, x, xb);
  gemm8p<256, 1><<<512, 512, 0, stream>>>(xb, w1T, b1, nullptr, nullptr, hbuf, NM, 4096, 1024);
  gemm8p<128, 2><<<256, 512, 0, stream>>>(hbuf, w2T, b2, nullptr, nullptr, tmpf, NM, 1024, 4096);
  ln_res<0><<<8192, 256, 0, stream>>>(x, tmpf, g2, be2, (float*)d_out, nullptr);
}